// Round 7
// baseline (380.856 us; speedup 1.0000x reference)
//
#include <hip/hip_runtime.h>
#include <math.h>

#define BATCH 2048
#define N_TIME 2048
#define INPUT_SIZE 28
#define OUTPUT_SIZE 7
#define N_S 4
#define PERIOD 7
#define EMBED 9
#define SEAS_LEN (N_TIME + PERIOD)       // 2055
#define W_COUNT 288                      // len(range(0, 2014, 7))
#define WB_COUNT (W_COUNT * BATCH)       // 589824
#define INS_COLS 67                      // 28 + 35 + 4
#define OUT0_SIZE (WB_COUNT * INS_COLS)  // 39,518,208
#define OUT1_SIZE (WB_COUNT * OUTPUT_SIZE) // 4,128,768
#define LEV_SIZE (BATCH * N_TIME)
#define SEAS_SIZE (BATCH * SEAS_LEN)

// Single-kernel work split:
//   scan blocks (0..31): producer-consumer ES recurrence (code identical to
//     the proven round-4/6 scan), consumer wave publishes a per-slab
//     agent-scope release flag after vmcnt(0); scan blocks then EXIT.
//     ROUND-5 LESSON: scan blocks must never share tail code / LDS / steal
//     loops with other roles, or the compiler drops the y-buffer SROA
//     (VGPR 256->132 + scratch). Round-5's sync mechanism itself was correct.
//   copy blocks (32..511): X/S/out1 copy (no deps), then STATIC yin partition:
//     block cb serves slab cb&31, part cb>>5 (15 parts/slab), behind one
//     acquire-poll on the slab flag. No queues, no atomics beyond the flag.
// Deadlock-free: 66.5 KB LDS -> exactly 2 blocks/CU -> all 512 co-resident;
// blocks 0..31 dispatch first regardless.
#define M0_COPY (WB_COUNT * 39)              // 23,003,136 (X+S cols)
#define M_COPY  (M0_COPY + OUT1_SIZE)        // 27,131,904
#define COPY_BLOCKS 480
#define GRID1 (32 + COPY_BLOCKS)
#define CUNROLL 16

#define YIN_PER_SB (W_COUNT * 64 * INPUT_SIZE)   // 516096 per 64-row slab
#define YIN_PARTS  15
#define YIN_PART_SZ ((YIN_PER_SB + YIN_PARTS - 1) / YIN_PARTS)  // 34407

// ---------------------------------------------------------------------------
// Scan core (round-6 proven): producer = software-pipelined recurrence with
// modular-slot sbuf/rbuf (s_k = ns_{k-7} known 7 steps early -> level update
// is ONE carried fma); consumer = tile transpose + coalesced stores.
// ---------------------------------------------------------------------------
struct ScanState {
    float lev, lsms, seas_sms, oma, oms;
    float sbuf[PERIOD];   // slot j%7 holds s_{t0+j}
    float rbuf[PERIOD];   // slot j%7 holds lsms * rcp(s_{t0+j})
    float yp, sp, rnlp, rnsp;
};

template<bool FIRST, bool LAST, bool PREF>
__device__ __forceinline__ void scan_chunk(
    int base, int l,
    const float* __restrict__ Yb,
    float (&cur)[64], float (&nxt)[64],
    float (*__restrict__ tl)[65], float (*__restrict__ ts)[65],
    ScanState& st)
{
    if (PREF) {
#pragma unroll
        for (int k = 0; k < 64; k += 4)
            *(float4*)&nxt[k] = *(const float4*)(Yb + base + 64 + k);
    }
    tl[l][0] = st.lev;                 // carry-in: levels col `base`
#pragma unroll
    for (int k = 0; k < 64; ++k) {
        if (!LAST || k < 63) {         // last chunk has 63 steps
            float y  = (k < 63) ? cur[k + 1] : nxt[0];
            float s0 = st.sbuf[k % 7];
            float nl = fmaf(st.oma, st.lev, y * st.rbuf[k % 7]);
            st.lev = nl;
            tl[l][k + 1] = nl;         // levels col base+k+1
            if (!FIRST || k > 0) {     // finish PREVIOUS step's seasonal
                float u  = st.yp * st.rnlp;
                float ns = fmaf(st.oms, st.sp, st.seas_sms * u);
                ts[l][k] = ns;                 // seasonal col base+7+k
                st.sbuf[(k + 6) % 7] = ns;     // consumed at k+6
                if (!FIRST || k > 1)
                    st.rbuf[(k + 5) % 7] = st.lsms * st.rnsp; // for k+5
                st.rnsp = __builtin_amdgcn_rcpf(ns);
            }
            float rnl = __builtin_amdgcn_rcpf(nl);   // consumed next step
            st.yp = y; st.sp = s0; st.rnlp = rnl;
        }
    }
    if (LAST) {                        // drain pipeline: ns_{2046}
        float u  = st.yp * st.rnlp;
        float ns = fmaf(st.oms, st.sp, st.seas_sms * u);
        ts[l][63] = ns;                // seasonal col 2054
    } else {
        // slot-base drift: next chunk's t0 advances by 64 (== 1 mod 7)
        float t0s = st.sbuf[0], t0r = st.rbuf[0];
#pragma unroll
        for (int q = 0; q < PERIOD - 1; ++q) {
            st.sbuf[q] = st.sbuf[q + 1];
            st.rbuf[q] = st.rbuf[q + 1];
        }
        st.sbuf[PERIOD - 1] = t0s;
        st.rbuf[PERIOD - 1] = t0r;
    }
    asm volatile("s_waitcnt lgkmcnt(0)" ::: "memory");
    __builtin_amdgcn_s_barrier();
}

__device__ __forceinline__ void drain_chunk(
    int base, int jr, int km, int r0,
    const float (*__restrict__ tl)[65], const float (*__restrict__ ts)[65],
    float* __restrict__ levels, float* __restrict__ seasonal)
{
    __builtin_amdgcn_s_barrier();      // wait for producer to finish this tile
    asm volatile("" ::: "memory");
#pragma unroll
    for (int j0 = 0; j0 < 64; j0 += 4) {
        int j = j0 + jr;
        float vl[4], vs[4];
#pragma unroll
        for (int i = 0; i < 4; ++i) { vl[i] = tl[j][km + i]; vs[i] = ts[j][km + i]; }
        float4 v4; v4.x = vl[0]; v4.y = vl[1]; v4.z = vl[2]; v4.w = vl[3];
        *(float4*)(levels + (size_t)(r0 + j) * N_TIME + base + km) = v4;
        float* srow = seasonal + (size_t)(r0 + j) * SEAS_LEN + base + 7 + km;
#pragma unroll
        for (int i = 0; i < 4; ++i) srow[i] = vs[i];
    }
    asm volatile("s_waitcnt lgkmcnt(0)" ::: "memory");
}

__device__ __forceinline__ void copy_addr(
    unsigned g,
    const float* __restrict__ Y, const float* __restrict__ X,
    const float* __restrict__ S,
    float* __restrict__ out0, float* __restrict__ out1,
    const float*& src, float*& dst)
{
    if (g < M0_COPY) {                 // out0 cols 28..66 (X then S)
        unsigned wb = g / 39u;
        int jj = (int)(g - wb * 39u);
        int w  = (int)(wb >> 11);
        int b  = (int)(wb & (BATCH - 1));
        src = (jj < 35) ? &X[b * N_TIME + w * 7 + jj]
                        : &S[b * N_S + (jj - 35)];
        dst = &out0[(size_t)wb * 67u + 28u + (unsigned)jj];
    } else {                           // out1
        unsigned e  = g - M0_COPY;
        unsigned wb = e / 7u;
        int m  = (int)(e - wb * 7u);
        int w  = (int)(wb >> 11);
        int b  = (int)(wb & (BATCH - 1));
        src = &Y[b * N_TIME + w * 7 + INPUT_SIZE + m];
        dst = &out1[e];
    }
}

// yin for slab sb, part p: elements [p*34407, min(+34407, 516096)) of the
// slab's (288 windows x 64 rows x 28 cols) y_in space. __noinline__ so this
// body cannot perturb the scan path's unroll/SROA decisions (round-5 lesson).
__device__ __noinline__ void yin_part(
    int sb, int p, int tid,
    const float* __restrict__ Y, const float* __restrict__ levels,
    const float* __restrict__ seasonal, float* __restrict__ out0)
{
    const int start = p * YIN_PART_SZ;
    const int end   = (start + YIN_PART_SZ < YIN_PER_SB) ? start + YIN_PART_SZ
                                                         : YIN_PER_SB;
    int e = start + tid;
#pragma unroll 1
    for (; e + 7 * 128 < end; e += 8 * 128) {
        float yv[8], lv[8], sv[8]; size_t dst[8];
#pragma unroll
        for (int u = 0; u < 8; ++u) {
            int ee = e + u * 128;
            unsigned w    = (unsigned)ee / 1792u;      // 64*28
            unsigned rem  = (unsigned)ee - w * 1792u;
            unsigned brel = rem / 28u;
            unsigned j    = rem - brel * 28u;
            int b  = sb * 64 + (int)brel;
            int t0 = (int)w * 7;
            yv[u] = Y[b * N_TIME + t0 + (int)j];
            lv[u] = levels[b * N_TIME + t0 + INPUT_SIZE - 1];
            sv[u] = seasonal[b * SEAS_LEN + t0 + (int)j];
            dst[u] = ((size_t)w * BATCH + (size_t)b) * 67u + j;
        }
#pragma unroll
        for (int u = 0; u < 8; ++u)
            out0[dst[u]] = __logf(yv[u] * __builtin_amdgcn_rcpf(lv[u] * sv[u]));
    }
#pragma unroll 1
    for (; e < end; e += 128) {
        unsigned w    = (unsigned)e / 1792u;
        unsigned rem  = (unsigned)e - w * 1792u;
        unsigned brel = rem / 28u;
        unsigned j    = rem - brel * 28u;
        int b  = sb * 64 + (int)brel;
        int t0 = (int)w * 7;
        float yv = Y[b * N_TIME + t0 + (int)j];
        float lv = levels[b * N_TIME + t0 + INPUT_SIZE - 1];
        float sv = seasonal[b * SEAS_LEN + t0 + (int)j];
        out0[((size_t)w * BATCH + (size_t)b) * 67u + j] =
            __logf(yv * __builtin_amdgcn_rcpf(lv * sv));
    }
}

__global__ __launch_bounds__(128, 1) void es_scan_plus(
    const float* __restrict__ Y, const int* __restrict__ idxs,
    const float* __restrict__ emb, const float* __restrict__ X,
    const float* __restrict__ S,
    float* __restrict__ levels, float* __restrict__ seasonal,
    float* __restrict__ out0, float* __restrict__ out1,
    int* __restrict__ flags)
{
    __shared__ float tl[2][64][65];
    __shared__ float ts[2][64][65];
    const int tid = threadIdx.x;
    const int l   = tid & 63;

    if (blockIdx.x >= 32) {
        // ------- copy blocks: 16-deep gather/scatter, then static yin -------
        const int cb = (int)blockIdx.x - 32;
        const unsigned stride = COPY_BLOCKS * 128;
        unsigned g = (unsigned)cb * 128 + tid;
#pragma unroll 1
        for (; g + (CUNROLL - 1) * stride < M_COPY; g += stride * CUNROLL) {
            const float* src[CUNROLL]; float* dst[CUNROLL]; float v[CUNROLL];
#pragma unroll
            for (int u = 0; u < CUNROLL; ++u)
                copy_addr(g + (unsigned)u * stride, Y, X, S, out0, out1, src[u], dst[u]);
#pragma unroll
            for (int u = 0; u < CUNROLL; ++u) v[u] = *src[u];
#pragma unroll
            for (int u = 0; u < CUNROLL; ++u) *dst[u] = v[u];
        }
#pragma unroll 1
        for (; g < M_COPY; g += stride) {
            const float* src; float* dst;
            copy_addr(g, Y, X, S, out0, out1, src, dst);
            *dst = *src;
        }
        // wait for this block's slab, then do its yin part
        const int sb = cb & 31;
        const int p  = cb >> 5;
        if (tid == 0) {
            while (__hip_atomic_load(&flags[sb], __ATOMIC_ACQUIRE,
                                     __HIP_MEMORY_SCOPE_AGENT) == 0)
                __builtin_amdgcn_s_sleep(16);
        }
        __syncthreads();
        yin_part(sb, p, tid, Y, levels, seasonal, out0);
        return;
    }

    const int r0 = blockIdx.x * 64;
    if (tid < 64) {
        // ---------------- producer wave: the recurrence (no global stores) ----
        const int b = r0 + l;
        const float* Yb = Y + (size_t)b * N_TIME;
        const float* e  = emb + (size_t)idxs[b] * EMBED;
        ScanState st;
        st.lsms     = 1.0f / (1.0f + __expf(-e[0]));
        st.seas_sms = 1.0f / (1.0f + __expf(-e[1]));
        st.oma = 1.0f - st.lsms;
        st.oms = 1.0f - st.seas_sms;
        float is[PERIOD];
#pragma unroll
        for (int j = 0; j < PERIOD; ++j) is[j] = __expf(e[2 + j]);
        st.lev = Yb[0] / is[0];
        ts[0][l][0] = is[0];           // seasonal col 7 via tile (chunk 0)
#pragma unroll
        for (int j = 0; j < PERIOD; ++j) st.sbuf[j] = is[(j + 1) % PERIOD];
#pragma unroll
        for (int j = 0; j < PERIOD; ++j)
            st.rbuf[j] = st.lsms * __builtin_amdgcn_rcpf(st.sbuf[j]);
        st.yp = 0.0f; st.sp = 1.0f; st.rnlp = 1.0f; st.rnsp = 1.0f;

        float ya[64], yb2[64];
#pragma unroll
        for (int k = 0; k < 64; k += 4)
            *(float4*)&ya[k] = *(const float4*)(Yb + k);

        scan_chunk<true,  false, true >(0, l, Yb, ya, yb2, tl[0], ts[0], st);
#pragma unroll 1
        for (int cc = 0; cc < 15; ++cc) {
            scan_chunk<false, false, true>(64  + cc * 128, l, Yb, yb2, ya, tl[1], ts[1], st);
            scan_chunk<false, false, true>(128 + cc * 128, l, Yb, ya, yb2, tl[0], ts[0], st);
        }
        scan_chunk<false, true,  false>(1984, l, Yb, yb2, ya, tl[1], ts[1], st);
    } else {
        // ------- consumer wave: seasonal[0..6] + transpose stores + flag -------
        const int b = r0 + l;
        {   // here (not producer) so the flag orders ALL of this slab's stores
            const float* e = emb + (size_t)idxs[b] * EMBED;
            float* seab = seasonal + (size_t)b * SEAS_LEN;
#pragma unroll
            for (int j = 0; j < PERIOD; ++j) seab[j] = __expf(e[2 + j]);
        }
        const int jr = l >> 4;
        const int km = (l & 15) * 4;
#pragma unroll 1
        for (int c = 0; c < 32; ++c)
            drain_chunk(c * 64, jr, km, r0, tl[c & 1], ts[c & 1], levels, seasonal);
        asm volatile("s_waitcnt vmcnt(0)" ::: "memory");
        if (l == 0)
            __hip_atomic_store(&flags[blockIdx.x], 1, __ATOMIC_RELEASE,
                               __HIP_MEMORY_SCOPE_AGENT);
    }
    // scan blocks exit here — no shared tail code with other roles
}

extern "C" void kernel_launch(void* const* d_in, const int* in_sizes, int n_in,
                              void* d_out, int out_size, void* d_ws, size_t ws_size,
                              hipStream_t stream) {
    const float* S    = (const float*)d_in[0];
    const float* Y    = (const float*)d_in[1];
    const float* X    = (const float*)d_in[2];
    const int*   idxs = (const int*)d_in[3];
    const float* emb  = (const float*)d_in[4];

    float* out      = (float*)d_out;
    float* out_ins  = out;                                    // (W,B,67)
    float* out_outs = out + OUT0_SIZE;                        // (W,B,7)
    float* levels   = out + OUT0_SIZE + OUT1_SIZE;            // (B,2048)
    float* seasonal = out + OUT0_SIZE + OUT1_SIZE + LEV_SIZE; // (B,2055)

    int* flags = (int*)d_ws;           // [32]
    hipMemsetAsync(d_ws, 0, 32 * sizeof(int), stream);

    es_scan_plus<<<GRID1, 128, 0, stream>>>(
        Y, idxs, emb, X, S, levels, seasonal, out_ins, out_outs, flags);
}